// Round 1
// baseline (1316.325 us; speedup 1.0000x reference)
//
#include <hip/hip_runtime.h>

// out[b,c,i,j] = x[b,c,2i,2j] * 0.5f  (Haar DWT sum collapses algebraically)
// x: (16,64,512,512) fp32, out: (16,64,256,256) fp32.
// Each thread: 4 output columns -> two float4 loads (8 input cols), one float4 store.

__global__ __launch_bounds__(256) void haar_down_kernel(
    const float* __restrict__ in, float* __restrict__ out, int total_groups) {
    int t = blockIdx.x * blockDim.x + threadIdx.x;
    if (t >= total_groups) return;

    int row = t >> 6;        // output row over B*C*Ho = 16*64*256 = 262144 rows
    int grp = t & 63;        // which 4-wide group within the 256-wide output row
    int bc  = row >> 8;      // image index (B*C)
    int ho  = row & 255;     // output row within image

    size_t in_off = (((size_t)bc * 512) + (size_t)(ho << 1)) * 512 + ((size_t)grp << 3);
    const float4 v0 = *reinterpret_cast<const float4*>(in + in_off);
    const float4 v1 = *reinterpret_cast<const float4*>(in + in_off + 4);

    float4 o;
    o.x = v0.x * 0.5f;
    o.y = v0.z * 0.5f;
    o.z = v1.x * 0.5f;
    o.w = v1.z * 0.5f;

    size_t out_off = ((size_t)row << 8) + ((size_t)grp << 2);
    *reinterpret_cast<float4*>(out + out_off) = o;
}

extern "C" void kernel_launch(void* const* d_in, const int* in_sizes, int n_in,
                              void* d_out, int out_size, void* d_ws, size_t ws_size,
                              hipStream_t stream) {
    const float* x = (const float*)d_in[0];
    float* out = (float*)d_out;

    // out_size = 16*64*256*256 = 67108864; 4 outputs per thread
    int total_groups = out_size / 4;            // 16777216
    int block = 256;
    int grid = (total_groups + block - 1) / block;  // 65536
    haar_down_kernel<<<grid, block, 0, stream>>>(x, out, total_groups);
}